// Round 11
// baseline (4163.454 us; speedup 1.0000x reference)
//
#include <hip/hip_runtime.h>
#include <hip/hip_bf16.h>
#include <math.h>

// ---------------- model dims ----------------
#define Bsz 32
#define Cdim 768
#define Mdim 3072
#define Ldim 12
#define NTOK 210            // real tokens per image: 14*(14+1)
#define NTOKP 256           // padded tokens per image
#define TPAD (Bsz*NTOKP)    // 8192 padded token rows
#define NPATCH 196
#define PROWS (Bsz*NPATCH)  // 6272 = 49*128
#define NCls 1000

typedef __hip_bfloat16 bf16;
typedef __attribute__((ext_vector_type(8))) short bfrag;   // 8 bf16 = 4 VGPR
typedef __attribute__((ext_vector_type(4))) float f32x4;

enum { EPI_NONE = 0, EPI_PHI = 1, EPI_GELU = 2, EPI_RESID = 3 };

__device__ __forceinline__ void gl_lds16(const void* g, void* l) {
    __builtin_amdgcn_global_load_lds(
        (const __attribute__((address_space(1))) unsigned*)g,
        (__attribute__((address_space(3))) unsigned*)l, 16, 0, 0);
}

__device__ __forceinline__ void stv(float* p, float v) { *p = v; }
__device__ __forceinline__ void stv(bf16* p, float v)  { *p = __float2bfloat16(v); }

__device__ __forceinline__ float epi_val(int EPI, float v) { return v; }

// ---- XCD-aware bijective swizzle (T1/m204) ----
__device__ __forceinline__ void xcd_swizzle(int& bx, int& by, int& bz)
{
    const int gx = gridDim.x, gy = gridDim.y;
    const int nwg = gx * gy * gridDim.z;
    int flat = (blockIdx.z * gy + blockIdx.y) * gx + blockIdx.x;
    int q8 = nwg >> 3, r8 = nwg & 7;
    int xcd = flat & 7, loc = flat >> 3;
    flat = ((xcd < r8) ? xcd * (q8 + 1) : r8 * (q8 + 1) + (xcd - r8) * q8) + loc;
    bx = flat % gx;
    int tmp = flat / gx;
    by = tmp % gy;
    bz = tmp / gy;
}

// -------------------------------------------------------------------------
// 8-phase 256x256 MFMA NT-GEMM (m201-style, derived waits), 512 thr / 8 waves
// (2M x 4N, wave tile 128x64). BK=64 per K-tile, 4 phases per K-tile, each
// phase = {issue 1 half-tile prefetch, ds_read 4-8 x b128, lgkmcnt(0)+
// sched_barrier, setprio(1), 16 MFMA, setprio(0), barrier}.
// LDS = 8 half-slots x 16KB ring (128KB). Half-tile h = 4t+q (q: A0,A1,B0,B1)
// staged during tile t-1 (phase q) into slot h&7; WAR-safe because slot h&7's
// previous occupant (h-8 = tile t-3... actually 4(t-1)+q) was last read in
// tile t-1... wait: h=4(t+1)+p issued at t.p targets slot previously holding
// 4(t-1)+p, last read during tile t-1, all waves past that read's phase
// barrier before any t.p issue. Validation ONCE per K-tile at p0: vmcnt(2)
// (outstanding = this tile's 4 halves issued last tile + 1 half just issued;
// allow the newest 2 loads) -> counted wait, full drain only at the tail.
// T2 chunk-XOR swizzle (phys 16B-chunk = logical ^ (row&7)): linear gl_lds
// dest + inverse-swizzled global source + swizzled ds_read (rule 21).
// M%256==0, N%256==0, K%64==0, K/64>=2. Batched via blockIdx.z.
// -------------------------------------------------------------------------
template<int EPI, bool HAS_BIAS, typename OUTT>
__global__ __launch_bounds__(512, 1)
void gemm8p(const bf16* __restrict__ A, const bf16* __restrict__ B,
            const float* __restrict__ bias, OUTT* __restrict__ C,
            int M, int N, int K, long sA, long sB, long sC, int zc)
{
    int bx, by, bz;
    xcd_swizzle(bx, by, bz);
    A += (long)bz * sA; B += (long)bz * sB; C += (long)bz * sC;
    const int m0 = by * 256, n0 = bx * 256;

    __shared__ __align__(16) bf16 sh[8 * 8192];   // 8 half-slots x 16KB

    const int tid  = threadIdx.x;
    const int lane = tid & 63, wid = tid >> 6;
    const int wr = wid >> 2, wc = wid & 3;        // 2M x 4N wave grid
    const int lr = lane & 15, lg = lane >> 4;
    const int rxor = lr & 7;

    f32x4 acc[8][4];
    #pragma unroll
    for (int i = 0; i < 8; ++i)
        #pragma unroll
        for (int j = 0; j < 4; ++j)
            acc[i][j] = f32x4{0.f, 0.f, 0.f, 0.f};

    // staging (per thread, 2 insts per 128x64 half-tile):
    // inst ii covers LDS row r = ii*64 + tid/8, 16B chunk tid&7 (linear dest);
    // global source chunk inverse-swizzled by r&7 = (tid>>3)&7.
    const int srow   = tid >> 3;                               // 0..63
    const int schunk = ((tid & 7) ^ ((tid >> 3) & 7)) * 8;     // elems

    auto issue_half = [&](int h) {
        const int q = h & 3;                       // 0:A0 1:A1 2:B0 3:B1
        const bf16* P  = (q & 2) ? B : A;
        const int base = ((q & 2) ? n0 : m0) + ((q & 1) << 7);
        const long kof = (long)(h >> 2) * 64 + schunk;
        bf16* s = sh + (size_t)(h & 7) * 8192;
        #pragma unroll
        for (int ii = 0; ii < 2; ++ii) {
            const int r = ii * 64 + srow;
            gl_lds16(P + (long)(base + r) * K + kof, s + ii * 4096 + tid * 8);
        }
    };

    // prologue: tile 0's four halves
    issue_half(0); issue_half(1); issue_half(2); issue_half(3);

    const int kt = K >> 6;
    for (int t = 0; t < kt; ++t) {
        const bf16* Ah = sh + (size_t)((4 * t + wr) & 7) * 8192;
        const bf16* Bh = sh + (size_t)((4 * t + 2 + (wc >> 1)) & 7) * 8192;
        const int brow0 = (wc & 1) * 64 + lr;
        bfrag b4[4];

        #pragma unroll
        for (int p = 0; p < 4; ++p) {
            if (t + 1 < kt) issue_half(4 * (t + 1) + p);    // prefetch
            if (p == 0) {                                    // validate tile t
                if (t + 1 < kt) asm volatile("s_waitcnt vmcnt(2)" ::: "memory");
                else            asm volatile("s_waitcnt vmcnt(0)" ::: "memory");
                __builtin_amdgcn_s_barrier();
            }
            const int ks = p >> 1, ih = p & 1;
            const int kchunk = (((ks * 4 + lg) ^ rxor)) * 8;
            bfrag a4[4];
            #pragma unroll
            for (int ii = 0; ii < 4; ++ii)
                a4[ii] = *(const bfrag*)(Ah + ((ih * 4 + ii) * 16 + lr) * 64 + kchunk);
            if (ih == 0) {
                #pragma unroll
                for (int j = 0; j < 4; ++j)
                    b4[j] = *(const bfrag*)(Bh + (brow0 + j * 16) * 64 + kchunk);
            }
            asm volatile("s_waitcnt lgkmcnt(0)" ::: "memory");
            __builtin_amdgcn_sched_barrier(0);               // rule 18
            __builtin_amdgcn_s_setprio(1);
            #pragma unroll
            for (int ii = 0; ii < 4; ++ii)
                #pragma unroll
                for (int j = 0; j < 4; ++j)
                    acc[ih * 4 + ii][j] = __builtin_amdgcn_mfma_f32_16x16x32_bf16(
                        a4[ii], b4[j], acc[ih * 4 + ii][j], 0, 0, 0);
            __builtin_amdgcn_s_setprio(0);
            __builtin_amdgcn_s_barrier();
        }
    }

    // epilogue: C/D mapping col=lane&15, row=(lane>>4)*4+reg  [m89/m91]
    const int cidx  = lane & 15;
    const int rbase = (lane >> 4) * 4;
    #pragma unroll
    for (int i = 0; i < 8; ++i) {
        #pragma unroll
        for (int j = 0; j < 4; ++j) {
            const int gn = n0 + wc * 64 + j * 16 + cidx;
            float bv = HAS_BIAS ? bias[gn] : 0.f;
            #pragma unroll
            for (int r = 0; r < 4; ++r) {
                const int gm = m0 + wr * 128 + i * 16 + rbase + r;
                float v = acc[i][j][r] + bv;
                long idx = (long)gm * N + gn;
                if (EPI == EPI_PHI) {
                    v = (v > 0.f) ? (v + 1.f) : expf(v);
                    if (gn >= zc) v = 0.f;
                }
                if (EPI == EPI_GELU)  v = 0.5f * v * (1.f + erff(v * 0.70710678118654752f));
                if (EPI == EPI_RESID) v += ((const float*)C)[idx];
                stv(&C[idx], v);
            }
        }
    }
}

// -------------------------------------------------------------------------
// 128x128 BK=64 kernel (R7, best-so-far) for the smaller/odd-shaped GEMMs.
// -------------------------------------------------------------------------
template<int EPI, bool HAS_BIAS, typename OUTT>
__global__ __launch_bounds__(256, 2)
void gemm_bt(const bf16* __restrict__ A, const bf16* __restrict__ B,
             const float* __restrict__ bias, OUTT* __restrict__ C,
             int M, int N, int K, long sA, long sB, long sC, int zc)
{
    int bx, by, bz;
    xcd_swizzle(bx, by, bz);

    A += (long)bz * sA; B += (long)bz * sB; C += (long)bz * sC;
    const int m0 = by * 128, n0 = bx * 128;

    __shared__ __align__(16) bf16 sh[2 * 16384];

    const int tid  = threadIdx.x;
    const int lane = tid & 63, wid = tid >> 6;
    const int wr = wid >> 1, wc = wid & 1;
    const int lr = lane & 15, lg = lane >> 4;

    f32x4 acc[4][4];
    #pragma unroll
    for (int i = 0; i < 4; ++i)
        #pragma unroll
        for (int j = 0; j < 4; ++j)
            acc[i][j] = f32x4{0.f, 0.f, 0.f, 0.f};

    const int srow = tid >> 3;
    const int scol = ((tid & 7) ^ ((tid >> 3) & 7)) * 8;
    const bf16* gA = A + (long)(m0 + srow) * K + scol;
    const bf16* gB = B + (long)(n0 + srow) * K + scol;

    auto stage = [&](int slot) {
        bf16* s = sh + slot * 16384;
        #pragma unroll
        for (int L = 0; L < 4; ++L)
            gl_lds16(gA + (long)(L * 32) * K, s + L * 2048 + tid * 8);
        #pragma unroll
        for (int L = 0; L < 4; ++L)
            gl_lds16(gB + (long)(L * 32) * K, s + 8192 + L * 2048 + tid * 8);
        gA += 64; gB += 64;
    };

    const int rxor = lr & 7;
    const int arow = (wr * 64 + lr) * 64;
    const int brow = (wc * 64 + lr) * 64;

    const int kt = K >> 6;
    stage(0);

    for (int t = 0; t < kt; ++t) {
        if (t + 1 < kt) {
            stage((t + 1) & 1);
            asm volatile("s_waitcnt vmcnt(8)" ::: "memory");
        } else {
            asm volatile("s_waitcnt vmcnt(0)" ::: "memory");
        }
        __builtin_amdgcn_s_barrier();

        const bf16* Ab = sh + (t & 1) * 16384;
        const bf16* Bb = Ab + 8192;
        bfrag a[4][2], b[4][2];
        #pragma unroll
        for (int i = 0; i < 4; ++i)
            #pragma unroll
            for (int ks = 0; ks < 2; ++ks)
                a[i][ks] = *(const bfrag*)(Ab + arow + i * 1024 + ((ks * 4 + lg) ^ rxor) * 8);
        #pragma unroll
        for (int j = 0; j < 4; ++j)
            #pragma unroll
            for (int ks = 0; ks < 2; ++ks)
                b[j][ks] = *(const bfrag*)(Bb + brow + j * 1024 + ((ks * 4 + lg) ^ rxor) * 8);

        __builtin_amdgcn_s_setprio(1);
        #pragma unroll
        for (int ks = 0; ks < 2; ++ks)
            #pragma unroll
            for (int i = 0; i < 4; ++i)
                #pragma unroll
                for (int j = 0; j < 4; ++j)
                    acc[i][j] = __builtin_amdgcn_mfma_f32_16x16x32_bf16(a[i][ks], b[j][ks], acc[i][j], 0, 0, 0);
        __builtin_amdgcn_s_setprio(0);
        __builtin_amdgcn_s_barrier();
    }

    const int cidx  = lane & 15;
    const int rbase = (lane >> 4) * 4;
    #pragma unroll
    for (int i = 0; i < 4; ++i) {
        #pragma unroll
        for (int j = 0; j < 4; ++j) {
            const int gn = n0 + wc * 64 + j * 16 + cidx;
            float bv = HAS_BIAS ? bias[gn] : 0.f;
            #pragma unroll
            for (int r = 0; r < 4; ++r) {
                const int gm = m0 + wr * 64 + i * 16 + rbase + r;
                float v = acc[i][j][r] + bv;
                long idx = (long)gm * N + gn;
                if (EPI == EPI_PHI) {
                    v = (v > 0.f) ? (v + 1.f) : expf(v);
                    if (gn >= zc) v = 0.f;
                }
                if (EPI == EPI_GELU)  v = 0.5f * v * (1.f + erff(v * 0.70710678118654752f));
                if (EPI == EPI_RESID) v += ((const float*)C)[idx];
                stv(&C[idx], v);
            }
        }
    }
}

// ---------------- LayerNorm over C=768 per row ----------------
template<typename OUTT>
__global__ __launch_bounds__(256)
void ln_rows(const float* __restrict__ x, OUTT* __restrict__ y,
             const float* __restrict__ g, const float* __restrict__ bta)
{
    int r = blockIdx.x;
    const float* xr = x + (long)r * Cdim;
    OUTT* yr = y + (long)r * Cdim;
    int t = threadIdx.x;

    float v0 = xr[t], v1 = xr[t + 256], v2 = xr[t + 512];
    float s  = v0 + v1 + v2;
    float s2 = v0 * v0 + v1 * v1 + v2 * v2;
    #pragma unroll
    for (int o = 32; o > 0; o >>= 1) {
        s  += __shfl_down(s,  o, 64);
        s2 += __shfl_down(s2, o, 64);
    }
    __shared__ float sh[4], sh2[4];
    int wid = t >> 6;
    if ((t & 63) == 0) { sh[wid] = s; sh2[wid] = s2; }
    __syncthreads();
    float S  = sh[0] + sh[1] + sh[2] + sh[3];
    float S2 = sh2[0] + sh2[1] + sh2[2] + sh2[3];
    float mu  = S * (1.f / Cdim);
    float var = S2 * (1.f / Cdim) - mu * mu;
    float inv = rsqrtf(var + 1e-5f);
    stv(&yr[t],       (v0 - mu) * inv * g[t]       + bta[t]);
    stv(&yr[t + 256], (v1 - mu) * inv * g[t + 256] + bta[t + 256]);
    stv(&yr[t + 512], (v2 - mu) * inv * g[t + 512] + bta[t + 512]);
}

// ---------------- fp32 -> bf16 cast (8 elems/thread) ----------------
__global__ void cast_f2b(const float* __restrict__ in, bf16* __restrict__ out, long n)
{
    long i = ((long)blockIdx.x * 256 + threadIdx.x) * 8;
    if (i >= n) return;
    float4 v0 = *(const float4*)(in + i);
    float4 v1 = *(const float4*)(in + i + 4);
    union { bf16 b[8]; uint4 u; } t;
    t.b[0] = __float2bfloat16(v0.x); t.b[1] = __float2bfloat16(v0.y);
    t.b[2] = __float2bfloat16(v0.z); t.b[3] = __float2bfloat16(v0.w);
    t.b[4] = __float2bfloat16(v1.x); t.b[5] = __float2bfloat16(v1.y);
    t.b[6] = __float2bfloat16(v1.z); t.b[7] = __float2bfloat16(v1.w);
    *(uint4*)(out + i) = t.u;
}

// interleaved cast: dst layout per layer l = [Wq(l) CC][Wv(l) CC]
#define CCn (768*768)
__global__ void cast_qv(const float* __restrict__ Wq, const float* __restrict__ Wv,
                        bf16* __restrict__ dst)
{
    long i = ((long)blockIdx.x * 256 + threadIdx.x) * 8;
    if (i >= (long)Ldim * 2 * CCn) return;
    long l = i / (2 * CCn); long rem = i - l * 2 * CCn;
    const float* src = (rem < CCn) ? (Wq + l * CCn + rem) : (Wv + l * CCn + rem - CCn);
    float4 v0 = *(const float4*)(src);
    float4 v1 = *(const float4*)(src + 4);
    union { bf16 b[8]; uint4 u; } t;
    t.b[0] = __float2bfloat16(v0.x); t.b[1] = __float2bfloat16(v0.y);
    t.b[2] = __float2bfloat16(v0.z); t.b[3] = __float2bfloat16(v0.w);
    t.b[4] = __float2bfloat16(v1.x); t.b[5] = __float2bfloat16(v1.y);
    t.b[6] = __float2bfloat16(v1.z); t.b[7] = __float2bfloat16(v1.w);
    *(uint4*)(dst + i) = t.u;
}

// ---------------- im2col (bf16 out) for stride-16 patch conv ----------------
__global__ void im2col_patch(const float* __restrict__ x, bf16* __restrict__ out)
{
    long idx = (long)blockIdx.x * 256 + threadIdx.x;
    if (idx >= (long)PROWS * Cdim) return;
    int col = (int)(idx % Cdim);
    int row = (int)(idx / Cdim);
    int c = col >> 8, rem = col & 255, k = rem >> 4, l = rem & 15;
    int wp = row % 14; int t2 = row / 14; int hp = t2 % 14; int b = t2 / 14;
    out[idx] = __float2bfloat16(x[(((long)b * 3 + c) * 224 + hp * 16 + k) * 224 + wp * 16 + l]);
}

// h[b*256+n, c]: n<210 -> token value + pos_enc; n>=210 -> 0
__global__ void assemble_h(const float* __restrict__ pel,
                           const float* __restrict__ cls_tok,
                           const float* __restrict__ pos_enc,
                           float* __restrict__ h)
{
    long idx = (long)blockIdx.x * 256 + threadIdx.x;
    if (idx >= (long)TPAD * Cdim) return;
    int c = (int)(idx % Cdim);
    long t = idx / Cdim;
    int n = (int)(t % NTOKP); int b = (int)(t / NTOKP);
    if (n >= NTOK) { h[idx] = 0.f; return; }
    int hp = n / 15, w = n % 15;
    float pos = pos_enc[(long)c * NTOK + hp * 15 + w];
    float v = (w == 0) ? cls_tok[c]
                       : pel[((long)b * NPATCH + hp * 14 + (w - 1)) * Cdim + c];
    h[idx] = v + pos;
}

// cls_feat[b,c] = mean_hp h[b*256 + hp*15, c]
__global__ void cls_pool(const float* __restrict__ h, float* __restrict__ cf)
{
    int idx = blockIdx.x * 256 + threadIdx.x;
    if (idx >= Bsz * Cdim) return;
    int c = idx % Cdim, b = idx / Cdim;
    float s = 0.f;
    #pragma unroll
    for (int hp = 0; hp < 14; ++hp)
        s += h[((long)b * NTOKP + hp * 15) * Cdim + c];
    cf[idx] = s * (1.f / 14.f);
}

__global__ void head_gemm(const float* __restrict__ cf, const float* __restrict__ w,
                          const float* __restrict__ bias, float* __restrict__ out)
{
    int idx = blockIdx.x * 256 + threadIdx.x;
    if (idx >= Bsz * NCls) return;
    int j = idx % NCls, b = idx / NCls;
    const float* cr = cf + (long)b * Cdim;
    const float* wr = w + (long)j * Cdim;
    float s = 0.f;
    for (int c = 0; c < Cdim; ++c) s += cr[c] * wr[c];
    out[idx] = s + bias[j];
}

// -------------------------------------------------------------------------
extern "C" void kernel_launch(void* const* d_in, const int* in_sizes, int n_in,
                              void* d_out, int out_size, void* d_ws, size_t ws_size,
                              hipStream_t stream)
{
    const float* x       = (const float*)d_in[0];
    const float* patch_w = (const float*)d_in[1];
    const float* patch_b = (const float*)d_in[2];
    const float* pe_g    = (const float*)d_in[3];
    const float* pe_b    = (const float*)d_in[4];
    const float* cls_tok = (const float*)d_in[5];
    const float* pos_enc = (const float*)d_in[6];
    const float* Wq      = (const float*)d_in[7];
    const float* Wk      = (const float*)d_in[8];
    const float* Wv      = (const float*)d_in[9];
    const float* Wo_w    = (const float*)d_in[10];
    const float* Wo_b    = (const float*)d_in[11];
    const float* ln1_g   = (const float*)d_in[12];
    const float* ln1_b   = (const float*)d_in[13];
    const float* ln2_g   = (const float*)d_in[14];
    const float* ln2_b   = (const float*)d_in[15];
    const float* mlp1_w  = (const float*)d_in[16];
    const float* mlp1_b  = (const float*)d_in[17];
    const float* mlp2_w  = (const float*)d_in[18];
    const float* mlp2_b  = (const float*)d_in[19];
    const float* head_w  = (const float*)d_in[20];
    const float* head_b  = (const float*)d_in[21];

    // ---------------- workspace layout ----------------
    char* base = (char*)d_ws;
    size_t off = 0;
    auto take = [&](size_t bytes) -> char* {
        char* p = base + off; off += (bytes + 255) & ~(size_t)255; return p;
    };
    float* h    = (float*)take((size_t)TPAD * Cdim * 4);           // fp32 residual
    bf16*  xn   = (bf16*) take((size_t)TPAD * Cdim * 2);
    bf16*  pk   = (bf16*) take((size_t)TPAD * Cdim * 2);
    bf16*  pqvT = (bf16*) take((size_t)Bsz * 1536 * NTOKP * 2);    // [B][q0..767,v768..1535][256]
    char*  big  = take((size_t)TPAD * Mdim * 2);                   // 50.3 MB shared region
    bf16*  wbf  = (bf16*) take((size_t)85524480 * 2);              // bf16 weights
    if (off > ws_size) return;

    // big-region aliases (phase-disjoint)
    bf16*  hid = (bf16*)big;                                       // MLP phase
    bf16*  qv  = (bf16*)big;                                       // attn phase [B][768][768]
    bf16*  att = (bf16*)(big + (size_t)Bsz * Cdim * Cdim * 2);     // attn phase
    bf16*  im  = (bf16*)big;                                       // patch phase
    float* peo = (float*)(big + 9633792);
    float* pel = (float*)(big + 9633792 + 19267584);
    float* cf  = (float*)big;                                      // head phase

    // bf16 weight sub-buffers
    const long CC  = (long)Cdim * Cdim;             // 589,824
    const long nCC = (long)Ldim * CC;               // 7,077,888
    const long nMC = (long)Ldim * Mdim * Cdim;      // 28,311,552
    bf16* wqv_bf = wbf;                 // interleaved per layer: [wq CC][wv CC]
    bf16* wk_bf  = wqv_bf + 2 * nCC;
    bf16* wo_bf  = wk_bf + nCC;
    bf16* m1_bf  = wo_bf + nCC;
    bf16* m2_bf  = m1_bf + nMC;
    bf16* pw_bf  = m2_bf + nMC;

    auto cast = [&](const float* src, bf16* dst, long n) {
        cast_f2b<<<dim3((unsigned)((n / 8 + 255) / 256)), 256, 0, stream>>>(src, dst, n);
    };
    cast_qv<<<dim3((unsigned)((2 * nCC / 8 + 255) / 256)), 256, 0, stream>>>(Wq, Wv, wqv_bf);
    cast(Wk, wk_bf, nCC);
    cast(Wo_w, wo_bf, nCC); cast(mlp1_w, m1_bf, nMC); cast(mlp2_w, m2_bf, nMC);
    cast(patch_w, pw_bf, CC);

    // ---------------- patch embedding ----------------
    {
        long tot = (long)PROWS * Cdim;
        im2col_patch<<<dim3((unsigned)((tot + 255) / 256)), 256, 0, stream>>>(x, im);
        gemm_bt<EPI_NONE, true, float><<<dim3(6, 49, 1), 256, 0, stream>>>(
            im, pw_bf, patch_b, peo, PROWS, Cdim, Cdim, 0, 0, 0, 0);
        ln_rows<float><<<dim3(PROWS), 256, 0, stream>>>(peo, pel, pe_g, pe_b);
        long tot2 = (long)TPAD * Cdim;
        assemble_h<<<dim3((unsigned)((tot2 + 255) / 256)), 256, 0, stream>>>(
            pel, cls_tok, pos_enc, h);
    }

    // ---------------- transformer layers ----------------
    const long TNC = (long)NTOKP * Cdim;            // 196,608 per-batch activation stride
    const long QVS = (long)1536 * NTOKP;            // 393,216 per-batch pqvT stride
    for (int l = 0; l < Ldim; ++l) {
        const bf16*  wqv = wqv_bf + (long)l * 2 * CC;
        const bf16*  wk  = wk_bf + (long)l * CC;
        const bf16*  wo  = wo_bf + (long)l * CC;
        const bf16*  m1  = m1_bf + (long)l * Mdim * Cdim;
        const bf16*  m2  = m2_bf + (long)l * Mdim * Cdim;
        const float* wob = Wo_b  + (long)l * Cdim;
        const float* g1  = ln1_g + (long)l * Cdim;
        const float* b1  = ln1_b + (long)l * Cdim;
        const float* g2  = ln2_g + (long)l * Cdim;
        const float* b2  = ln2_b + (long)l * Cdim;
        const float* m1b = mlp1_b + (long)l * Mdim;
        const float* m2b = mlp2_b + (long)l * Cdim;

        ln_rows<bf16><<<dim3(TPAD), 256, 0, stream>>>(h, xn, g1, b1);

        // pqvT[b][c(0..1535)][n] = phi(sum_k wqv[c,k]*xn[b,n,k]) — 8-phase 256²
        gemm8p<EPI_PHI, false, bf16><<<dim3(1, 6, Bsz), 512, 0, stream>>>(
            wqv, xn, nullptr, pqvT, 1536, NTOKP, Cdim, 0, TNC, QVS, NTOK);
        // pk[t][d] = phi(sum_k xn[t,k]*wk[d,k])
        gemm_bt<EPI_PHI, false, bf16><<<dim3(6, TPAD / 128, 1), 256, 0, stream>>>(
            xn, wk, nullptr, pk, TPAD, Cdim, Cdim, 0, 0, 0, 1 << 30);

        // qv[b][c][d] = sum_n pqT[b,c,n]*pvT[b,d,n]
        gemm_bt<EPI_NONE, false, bf16><<<dim3(6, 6, Bsz), 256, 0, stream>>>(
            pqvT, pqvT + (long)768 * NTOKP, nullptr, qv, Cdim, Cdim, NTOKP,
            QVS, QVS, CC, 0);
        // att[b][n][c] = sum_d pk[b,n,d]*qv[b,c,d]
        gemm_bt<EPI_NONE, false, bf16><<<dim3(6, 2, Bsz), 256, 0, stream>>>(
            pk, qv, nullptr, att, NTOKP, Cdim, Cdim, TNC, CC, TNC, 0);
        // h += att @ wo^T + wob
        gemm_bt<EPI_RESID, true, float><<<dim3(6, TPAD / 128, 1), 256, 0, stream>>>(
            att, wo, wob, h, TPAD, Cdim, Cdim, 0, 0, 0, 0);

        ln_rows<bf16><<<dim3(TPAD), 256, 0, stream>>>(h, xn, g2, b2);

        // hid = gelu(xn @ m1^T + m1b) — 8-phase 256² (the big one)
        gemm8p<EPI_GELU, true, bf16><<<dim3(Mdim / 256, TPAD / 256, 1), 512, 0, stream>>>(
            xn, m1, m1b, hid, TPAD, Mdim, Cdim, 0, 0, 0, 0);
        // h += hid @ m2^T + m2b
        gemm_bt<EPI_RESID, true, float><<<dim3(6, TPAD / 128, 1), 256, 0, stream>>>(
            hid, m2, m2b, h, TPAD, Cdim, Mdim, 0, 0, 0, 0);
    }

    // ---------------- head ----------------
    cls_pool<<<dim3((Bsz * Cdim + 255) / 256), 256, 0, stream>>>(h, cf);
    head_gemm<<<dim3((Bsz * NCls + 255) / 256), 256, 0, stream>>>(
        cf, head_w, head_b, (float*)d_out);
}

// Round 12
// 3398.154 us; speedup vs baseline: 1.2252x; 1.2252x over previous
//
#include <hip/hip_runtime.h>
#include <hip/hip_bf16.h>
#include <math.h>

// ---------------- model dims ----------------
#define Bsz 32
#define Cdim 768
#define Mdim 3072
#define Ldim 12
#define NTOK 210            // real tokens per image: 14*(14+1)
#define NTOKP 256           // padded tokens (pqvT N / qv K only)
#define TD   (Bsz*NTOK)     // 6720 dense token rows
#define TDP  6784           // 53*128: M-grid padding for dense token GEMMs
#define NPATCH 196
#define PROWS (Bsz*NPATCH)  // 6272 = 49*128
#define NCls 1000
#define TBS  (NTOK*Cdim)    // 161280: per-batch dense token stride

typedef __hip_bfloat16 bf16;
typedef __attribute__((ext_vector_type(8))) short bfrag;   // 8 bf16 = 4 VGPR
typedef __attribute__((ext_vector_type(4))) float f32x4;

enum { EPI_NONE = 0, EPI_PHI = 1, EPI_GELU = 2, EPI_RESID = 3 };

__device__ __forceinline__ void gl_lds16(const void* g, void* l) {
    __builtin_amdgcn_global_load_lds(
        (const __attribute__((address_space(1))) unsigned*)g,
        (__attribute__((address_space(3))) unsigned*)l, 16, 0, 0);
}

__device__ __forceinline__ void stv(float* p, float v) { *p = v; }
__device__ __forceinline__ void stv(bf16* p, float v)  { *p = __float2bfloat16(v); }

// ---- XCD-aware bijective swizzle (T1/m204) ----
__device__ __forceinline__ void xcd_swizzle(int& bx, int& by, int& bz)
{
    const int gx = gridDim.x, gy = gridDim.y;
    const int nwg = gx * gy * gridDim.z;
    int flat = (blockIdx.z * gy + blockIdx.y) * gx + blockIdx.x;
    int q8 = nwg >> 3, r8 = nwg & 7;
    int xcd = flat & 7, loc = flat >> 3;
    flat = ((xcd < r8) ? xcd * (q8 + 1) : r8 * (q8 + 1) + (xcd - r8) * q8) + loc;
    bx = flat % gx;
    int tmp = flat / gx;
    by = tmp % gy;
    bz = tmp / gy;
}

// -------------------------------------------------------------------------
// MFMA NT-GEMM, 128x128 tile, BK=64, 2-slot dbuf (64KB LDS), counted
// vmcnt(8) (R7 config — best measured; schedule axis closed after R2-R11:
// serial/dbuf/4-deep/256^2/8-phase all <=+/-10% — short-K shapes sit at
// ~390 TF in this structure per the m102 shape curve).
// T2 chunk-XOR LDS swizzle (0 conflicts), T1 XCD swizzle, T5 setprio.
// C[m,n] = sum_k A[m,k]*B[n,k] (+bias) + epilogue. Batched via blockIdx.z.
// M%128==0, N%128==0, K%64==0 guaranteed by caller.
// zc:   EPI_PHI only — output cols gn>=zc written as 0 (token-pad cols).
// mrow: rows gm>=mrow are NOT written (per-batch dense-token write guard).
// -------------------------------------------------------------------------
template<int EPI, bool HAS_BIAS, typename OUTT>
__global__ __launch_bounds__(256, 2)
void gemm_bt(const bf16* __restrict__ A, const bf16* __restrict__ B,
             const float* __restrict__ bias, OUTT* __restrict__ C,
             int M, int N, int K, long sA, long sB, long sC, int zc, int mrow)
{
    int bx, by, bz;
    xcd_swizzle(bx, by, bz);

    A += (long)bz * sA; B += (long)bz * sB; C += (long)bz * sC;
    const int m0 = by * 128, n0 = bx * 128;

    __shared__ __align__(16) bf16 sh[2 * 16384];

    const int tid  = threadIdx.x;
    const int lane = tid & 63, wid = tid >> 6;
    const int wr = wid >> 1, wc = wid & 1;
    const int lr = lane & 15, lg = lane >> 4;

    f32x4 acc[4][4];
    #pragma unroll
    for (int i = 0; i < 4; ++i)
        #pragma unroll
        for (int j = 0; j < 4; ++j)
            acc[i][j] = f32x4{0.f, 0.f, 0.f, 0.f};

    // staging: linear LDS dest; inverse-swizzled GLOBAL 16B chunk (rule 21)
    const int srow = tid >> 3;                                   // 0..31
    const int scol = ((tid & 7) ^ ((tid >> 3) & 7)) * 8;         // elems
    const bf16* gA = A + (long)(m0 + srow) * K + scol;
    const bf16* gB = B + (long)(n0 + srow) * K + scol;

    auto stage = [&](int slot) {
        bf16* s = sh + slot * 16384;
        #pragma unroll
        for (int L = 0; L < 4; ++L)
            gl_lds16(gA + (long)(L * 32) * K, s + L * 2048 + tid * 8);
        #pragma unroll
        for (int L = 0; L < 4; ++L)
            gl_lds16(gB + (long)(L * 32) * K, s + 8192 + L * 2048 + tid * 8);
        gA += 64; gB += 64;
    };

    // fragment reads: phys 16B-chunk = logical ^ (row&7)
    const int rxor = lr & 7;
    const int arow = (wr * 64 + lr) * 64;
    const int brow = (wc * 64 + lr) * 64;

    const int kt = K >> 6;
    stage(0);

    for (int t = 0; t < kt; ++t) {
        if (t + 1 < kt) {
            stage((t + 1) & 1);
            asm volatile("s_waitcnt vmcnt(8)" ::: "memory");   // tile t landed
        } else {
            asm volatile("s_waitcnt vmcnt(0)" ::: "memory");
        }
        __builtin_amdgcn_s_barrier();

        const bf16* Ab = sh + (t & 1) * 16384;
        const bf16* Bb = Ab + 8192;
        bfrag a[4][2], b[4][2];
        #pragma unroll
        for (int i = 0; i < 4; ++i)
            #pragma unroll
            for (int ks = 0; ks < 2; ++ks)
                a[i][ks] = *(const bfrag*)(Ab + arow + i * 1024 + ((ks * 4 + lg) ^ rxor) * 8);
        #pragma unroll
        for (int j = 0; j < 4; ++j)
            #pragma unroll
            for (int ks = 0; ks < 2; ++ks)
                b[j][ks] = *(const bfrag*)(Bb + brow + j * 1024 + ((ks * 4 + lg) ^ rxor) * 8);

        __builtin_amdgcn_s_setprio(1);
        #pragma unroll
        for (int ks = 0; ks < 2; ++ks)
            #pragma unroll
            for (int i = 0; i < 4; ++i)
                #pragma unroll
                for (int j = 0; j < 4; ++j)
                    acc[i][j] = __builtin_amdgcn_mfma_f32_16x16x32_bf16(a[i][ks], b[j][ks], acc[i][j], 0, 0, 0);
        __builtin_amdgcn_s_setprio(0);
        __builtin_amdgcn_s_barrier();
    }

    // epilogue: C/D mapping col=lane&15, row=(lane>>4)*4+reg  [m89/m91]
    const int cidx  = lane & 15;
    const int rbase = (lane >> 4) * 4;
    #pragma unroll
    for (int i = 0; i < 4; ++i) {
        #pragma unroll
        for (int j = 0; j < 4; ++j) {
            const int gn = n0 + wc * 64 + j * 16 + cidx;
            float bv = HAS_BIAS ? bias[gn] : 0.f;
            #pragma unroll
            for (int r = 0; r < 4; ++r) {
                const int gm = m0 + wr * 64 + i * 16 + rbase + r;
                if (gm >= mrow) continue;            // dense-token write guard
                float v = acc[i][j][r] + bv;
                long idx = (long)gm * N + gn;
                if (EPI == EPI_PHI) {
                    v = (v > 0.f) ? (v + 1.f) : expf(v);
                    if (gn >= zc) v = 0.f;           // zero token-pad cols
                }
                if (EPI == EPI_GELU)  v = 0.5f * v * (1.f + erff(v * 0.70710678118654752f));
                if (EPI == EPI_RESID) v += ((const float*)C)[idx];
                stv(&C[idx], v);
            }
        }
    }
}

// ---------------- LayerNorm over C=768 per row ----------------
template<typename OUTT>
__global__ __launch_bounds__(256)
void ln_rows(const float* __restrict__ x, OUTT* __restrict__ y,
             const float* __restrict__ g, const float* __restrict__ bta)
{
    int r = blockIdx.x;
    const float* xr = x + (long)r * Cdim;
    OUTT* yr = y + (long)r * Cdim;
    int t = threadIdx.x;

    float v0 = xr[t], v1 = xr[t + 256], v2 = xr[t + 512];
    float s  = v0 + v1 + v2;
    float s2 = v0 * v0 + v1 * v1 + v2 * v2;
    #pragma unroll
    for (int o = 32; o > 0; o >>= 1) {
        s  += __shfl_down(s,  o, 64);
        s2 += __shfl_down(s2, o, 64);
    }
    __shared__ float sh[4], sh2[4];
    int wid = t >> 6;
    if ((t & 63) == 0) { sh[wid] = s; sh2[wid] = s2; }
    __syncthreads();
    float S  = sh[0] + sh[1] + sh[2] + sh[3];
    float S2 = sh2[0] + sh2[1] + sh2[2] + sh2[3];
    float mu  = S * (1.f / Cdim);
    float var = S2 * (1.f / Cdim) - mu * mu;
    float inv = rsqrtf(var + 1e-5f);
    stv(&yr[t],       (v0 - mu) * inv * g[t]       + bta[t]);
    stv(&yr[t + 256], (v1 - mu) * inv * g[t + 256] + bta[t + 256]);
    stv(&yr[t + 512], (v2 - mu) * inv * g[t + 512] + bta[t + 512]);
}

// ---------------- fp32 -> bf16 cast (8 elems/thread) ----------------
__global__ void cast_f2b(const float* __restrict__ in, bf16* __restrict__ out, long n)
{
    long i = ((long)blockIdx.x * 256 + threadIdx.x) * 8;
    if (i >= n) return;
    float4 v0 = *(const float4*)(in + i);
    float4 v1 = *(const float4*)(in + i + 4);
    union { bf16 b[8]; uint4 u; } t;
    t.b[0] = __float2bfloat16(v0.x); t.b[1] = __float2bfloat16(v0.y);
    t.b[2] = __float2bfloat16(v0.z); t.b[3] = __float2bfloat16(v0.w);
    t.b[4] = __float2bfloat16(v1.x); t.b[5] = __float2bfloat16(v1.y);
    t.b[6] = __float2bfloat16(v1.z); t.b[7] = __float2bfloat16(v1.w);
    *(uint4*)(out + i) = t.u;
}

// interleaved cast: dst layout per layer l = [Wq(l) CC][Wv(l) CC]
#define CCn (768*768)
__global__ void cast_qv(const float* __restrict__ Wq, const float* __restrict__ Wv,
                        bf16* __restrict__ dst)
{
    long i = ((long)blockIdx.x * 256 + threadIdx.x) * 8;
    if (i >= (long)Ldim * 2 * CCn) return;
    long l = i / (2 * CCn); long rem = i - l * 2 * CCn;
    const float* src = (rem < CCn) ? (Wq + l * CCn + rem) : (Wv + l * CCn + rem - CCn);
    float4 v0 = *(const float4*)(src);
    float4 v1 = *(const float4*)(src + 4);
    union { bf16 b[8]; uint4 u; } t;
    t.b[0] = __float2bfloat16(v0.x); t.b[1] = __float2bfloat16(v0.y);
    t.b[2] = __float2bfloat16(v0.z); t.b[3] = __float2bfloat16(v0.w);
    t.b[4] = __float2bfloat16(v1.x); t.b[5] = __float2bfloat16(v1.y);
    t.b[6] = __float2bfloat16(v1.z); t.b[7] = __float2bfloat16(v1.w);
    *(uint4*)(dst + i) = t.u;
}

// ---------------- im2col (bf16 out) for stride-16 patch conv ----------------
__global__ void im2col_patch(const float* __restrict__ x, bf16* __restrict__ out)
{
    long idx = (long)blockIdx.x * 256 + threadIdx.x;
    if (idx >= (long)PROWS * Cdim) return;
    int col = (int)(idx % Cdim);
    int row = (int)(idx / Cdim);
    int c = col >> 8, rem = col & 255, k = rem >> 4, l = rem & 15;
    int wp = row % 14; int t2 = row / 14; int hp = t2 % 14; int b = t2 / 14;
    out[idx] = __float2bfloat16(x[(((long)b * 3 + c) * 224 + hp * 16 + k) * 224 + wp * 16 + l]);
}

// DENSE h[b*210+n, c] = tok + pos_enc; rows >= TD zeroed (finite tail)
__global__ void assemble_h(const float* __restrict__ pel,
                           const float* __restrict__ cls_tok,
                           const float* __restrict__ pos_enc,
                           float* __restrict__ h)
{
    long idx = (long)blockIdx.x * 256 + threadIdx.x;
    if (idx >= (long)TDP * Cdim) return;
    int c = (int)(idx % Cdim);
    long t = idx / Cdim;
    if (t >= TD) { h[idx] = 0.f; return; }
    int n = (int)(t % NTOK); int b = (int)(t / NTOK);
    int hp = n / 15, w = n % 15;
    float pos = pos_enc[(long)c * NTOK + hp * 15 + w];
    float v = (w == 0) ? cls_tok[c]
                       : pel[((long)b * NPATCH + hp * 14 + (w - 1)) * Cdim + c];
    h[idx] = v + pos;
}

// cls_feat[b,c] = mean_hp h[b*210 + hp*15, c]   (dense layout)
__global__ void cls_pool(const float* __restrict__ h, float* __restrict__ cf)
{
    int idx = blockIdx.x * 256 + threadIdx.x;
    if (idx >= Bsz * Cdim) return;
    int c = idx % Cdim, b = idx / Cdim;
    float s = 0.f;
    #pragma unroll
    for (int hp = 0; hp < 14; ++hp)
        s += h[((long)b * NTOK + hp * 15) * Cdim + c];
    cf[idx] = s * (1.f / 14.f);
}

__global__ void head_gemm(const float* __restrict__ cf, const float* __restrict__ w,
                          const float* __restrict__ bias, float* __restrict__ out)
{
    int idx = blockIdx.x * 256 + threadIdx.x;
    if (idx >= Bsz * NCls) return;
    int j = idx % NCls, b = idx / NCls;
    const float* cr = cf + (long)b * Cdim;
    const float* wr = w + (long)j * Cdim;
    float s = 0.f;
    for (int c = 0; c < Cdim; ++c) s += cr[c] * wr[c];
    out[idx] = s + bias[j];
}

// -------------------------------------------------------------------------
extern "C" void kernel_launch(void* const* d_in, const int* in_sizes, int n_in,
                              void* d_out, int out_size, void* d_ws, size_t ws_size,
                              hipStream_t stream)
{
    const float* x       = (const float*)d_in[0];
    const float* patch_w = (const float*)d_in[1];
    const float* patch_b = (const float*)d_in[2];
    const float* pe_g    = (const float*)d_in[3];
    const float* pe_b    = (const float*)d_in[4];
    const float* cls_tok = (const float*)d_in[5];
    const float* pos_enc = (const float*)d_in[6];
    const float* Wq      = (const float*)d_in[7];
    const float* Wk      = (const float*)d_in[8];
    const float* Wv      = (const float*)d_in[9];
    const float* Wo_w    = (const float*)d_in[10];
    const float* Wo_b    = (const float*)d_in[11];
    const float* ln1_g   = (const float*)d_in[12];
    const float* ln1_b   = (const float*)d_in[13];
    const float* ln2_g   = (const float*)d_in[14];
    const float* ln2_b   = (const float*)d_in[15];
    const float* mlp1_w  = (const float*)d_in[16];
    const float* mlp1_b  = (const float*)d_in[17];
    const float* mlp2_w  = (const float*)d_in[18];
    const float* mlp2_b  = (const float*)d_in[19];
    const float* head_w  = (const float*)d_in[20];
    const float* head_b  = (const float*)d_in[21];

    // ---------------- workspace layout (dense tokens) ----------------
    char* base = (char*)d_ws;
    size_t off = 0;
    auto take = [&](size_t bytes) -> char* {
        char* p = base + off; off += (bytes + 255) & ~(size_t)255; return p;
    };
    float* h    = (float*)take((size_t)TDP * Cdim * 4);            // fp32 residual (dense)
    bf16*  xn   = (bf16*) take((size_t)TDP * Cdim * 2);
    bf16*  pk   = (bf16*) take((size_t)TDP * Cdim * 2);
    bf16*  pqvT = (bf16*) take((size_t)Bsz * 1536 * NTOKP * 2);    // [B][q,v][256]
    char*  big  = take((size_t)8192 * Mdim * 2);                   // 50.3 MB shared region
    bf16*  wbf  = (bf16*) take((size_t)85524480 * 2);              // bf16 weights
    if (off > ws_size) return;

    // big-region aliases (phase-disjoint)
    bf16*  hid = (bf16*)big;                                       // MLP phase [TDP][3072]
    bf16*  qv  = (bf16*)big;                                       // attn phase [B][768][768]
    bf16*  att = (bf16*)(big + (size_t)Bsz * Cdim * Cdim * 2);     // attn phase, dense [TDP][768]
    bf16*  im  = (bf16*)big;                                       // patch phase
    float* peo = (float*)(big + 9633792);
    float* pel = (float*)(big + 9633792 + 19267584);
    float* cf  = (float*)big;                                      // head phase

    // bf16 weight sub-buffers
    const long CC  = (long)Cdim * Cdim;             // 589,824
    const long nCC = (long)Ldim * CC;               // 7,077,888
    const long nMC = (long)Ldim * Mdim * Cdim;      // 28,311,552
    bf16* wqv_bf = wbf;                 // interleaved per layer: [wq CC][wv CC]
    bf16* wk_bf  = wqv_bf + 2 * nCC;
    bf16* wo_bf  = wk_bf + nCC;
    bf16* m1_bf  = wo_bf + nCC;
    bf16* m2_bf  = m1_bf + nMC;
    bf16* pw_bf  = m2_bf + nMC;

    auto cast = [&](const float* src, bf16* dst, long n) {
        cast_f2b<<<dim3((unsigned)((n / 8 + 255) / 256)), 256, 0, stream>>>(src, dst, n);
    };
    cast_qv<<<dim3((unsigned)((2 * nCC / 8 + 255) / 256)), 256, 0, stream>>>(Wq, Wv, wqv_bf);
    cast(Wk, wk_bf, nCC);
    cast(Wo_w, wo_bf, nCC); cast(mlp1_w, m1_bf, nMC); cast(mlp2_w, m2_bf, nMC);
    cast(patch_w, pw_bf, CC);

    const int HUGE = 1 << 30;

    // ---------------- patch embedding ----------------
    {
        long tot = (long)PROWS * Cdim;
        im2col_patch<<<dim3((unsigned)((tot + 255) / 256)), 256, 0, stream>>>(x, im);
        gemm_bt<EPI_NONE, true, float><<<dim3(6, 49, 1), 256, 0, stream>>>(
            im, pw_bf, patch_b, peo, PROWS, Cdim, Cdim, 0, 0, 0, 0, HUGE);
        ln_rows<float><<<dim3(PROWS), 256, 0, stream>>>(peo, pel, pe_g, pe_b);
        long tot2 = (long)TDP * Cdim;
        assemble_h<<<dim3((unsigned)((tot2 + 255) / 256)), 256, 0, stream>>>(
            pel, cls_tok, pos_enc, h);
    }

    // ---------------- transformer layers ----------------
    const long QVS = (long)1536 * NTOKP;            // 393,216 per-batch pqvT stride
    for (int l = 0; l < Ldim; ++l) {
        const bf16*  wqv = wqv_bf + (long)l * 2 * CC;
        const bf16*  wk  = wk_bf + (long)l * CC;
        const bf16*  wo  = wo_bf + (long)l * CC;
        const bf16*  m1  = m1_bf + (long)l * Mdim * Cdim;
        const bf16*  m2  = m2_bf + (long)l * Mdim * Cdim;
        const float* wob = Wo_b  + (long)l * Cdim;
        const float* g1  = ln1_g + (long)l * Cdim;
        const float* b1  = ln1_b + (long)l * Cdim;
        const float* g2  = ln2_g + (long)l * Cdim;
        const float* b2  = ln2_b + (long)l * Cdim;
        const float* m1b = mlp1_b + (long)l * Mdim;
        const float* m2b = mlp2_b + (long)l * Cdim;

        ln_rows<bf16><<<dim3(TDP), 256, 0, stream>>>(h, xn, g1, b1);

        // pqvT[b][c(0..1535)][n] = phi(sum_k wqv[c,k]*xn[b*210+n,k]); cols>=210 -> 0
        // (B reads rows n in [0,256) at dense stride 210: rows >=210 spill into
        //  batch b+1 / tail — garbage is multiplied into cols that zc zeroes.)
        gemm_bt<EPI_PHI, false, bf16><<<dim3(2, 12, Bsz), 256, 0, stream>>>(
            wqv, xn, nullptr, pqvT, 1536, NTOKP, Cdim, 0, TBS, QVS, NTOK, HUGE);
        // pk[t][d] = phi(sum_k xn[t,k]*wk[d,k])  — dense M (tail rows garbage, unused)
        gemm_bt<EPI_PHI, false, bf16><<<dim3(6, TDP / 128, 1), 256, 0, stream>>>(
            xn, wk, nullptr, pk, TDP, Cdim, Cdim, 0, 0, 0, HUGE, HUGE);

        // qv[b][c][d] = sum_n pqT[b,c,n]*pvT[b,d,n]  (K=256, zero-padded cols)
        gemm_bt<EPI_NONE, false, bf16><<<dim3(6, 6, Bsz), 256, 0, stream>>>(
            pqvT, pqvT + (long)768 * NTOKP, nullptr, qv, Cdim, Cdim, NTOKP,
            QVS, QVS, CC, HUGE, HUGE);
        // att[b*210+n][c] = sum_d pk[b*210+n,d]*qv[b,c,d]; rows n>=210 write-guarded
        gemm_bt<EPI_NONE, false, bf16><<<dim3(6, 2, Bsz), 256, 0, stream>>>(
            pk, qv, nullptr, att, NTOKP, Cdim, Cdim, TBS, CC, TBS, HUGE, NTOK);
        // h += att @ wo^T + wob   (dense M)
        gemm_bt<EPI_RESID, true, float><<<dim3(6, TDP / 128, 1), 256, 0, stream>>>(
            att, wo, wob, h, TDP, Cdim, Cdim, 0, 0, 0, HUGE, HUGE);

        ln_rows<bf16><<<dim3(TDP), 256, 0, stream>>>(h, xn, g2, b2);

        // hid = gelu(xn @ m1^T + m1b)   (dense M: 6784 vs 8192 = -17%)
        gemm_bt<EPI_GELU, true, bf16><<<dim3(Mdim / 128, TDP / 128, 1), 256, 0, stream>>>(
            xn, m1, m1b, hid, TDP, Mdim, Cdim, 0, 0, 0, HUGE, HUGE);
        // h += hid @ m2^T + m2b
        gemm_bt<EPI_RESID, true, float><<<dim3(6, TDP / 128, 1), 256, 0, stream>>>(
            hid, m2, m2b, h, TDP, Cdim, Mdim, 0, 0, 0, HUGE, HUGE);
    }

    // ---------------- head ----------------
    cls_pool<<<dim3((Bsz * Cdim + 255) / 256), 256, 0, stream>>>(h, cf);
    head_gemm<<<dim3((Bsz * NCls + 255) / 256), 256, 0, stream>>>(
        cf, head_w, head_b, (float*)d_out);
}